// Round 13
// baseline (100.483 us; speedup 1.0000x reference)
//
#include <hip/hip_runtime.h>

#define IH 512
#define IW 512
#define OH 502
#define OW 502
#define KS 11
#define HO 16                 /* output rows per strip */
#define NSTRIP 32             /* 32 strips of 16 rows */
#define NCH 48                /* 16*3 */
#define NBLK (NCH * NSTRIP)   /* 1536 */
#define NT 256                /* 4 independent waves; wave owns 128 out-cols */
#define LREG 144              /* per-wave per-row LDS region (138 used) */
#define C1f 0.0001f
#define C2f 0.0009f

// Gaussian(sigma=1.5, k=11) weights, precomputed in double precision.
__device__ __constant__ float g_w[KS] = {
    0.00102838f, 0.00759876f, 0.03600077f, 0.10936069f, 0.21300554f,
    0.26601173f, 0.21300554f, 0.10936069f, 0.03600077f, 0.00759876f,
    0.00102838f};

// Same-wave LDS RAW/WAR ordering only — no s_barrier anywhere in the loop.
#define WAITLDS() asm volatile("s_waitcnt lgkmcnt(0)" ::: "memory")

__global__ __launch_bounds__(NT, 1) void ssim_main(const float* __restrict__ x,
                                                   const float* __restrict__ y,
                                                   double* __restrict__ acc,
                                                   unsigned int* __restrict__ cnt,
                                                   float* __restrict__ out) {
    __shared__ float lds[4][5][2][LREG];   /* [wave][q][row][col] : 23 KB */
    __shared__ float red[4];

    const int t = threadIdx.x;
    const int w = t >> 6;                 // wave id: owns out-cols 128w..128w+127
    const int l = t & 63;
    const int ch = blockIdx.x / NSTRIP;
    const int strip = blockIdx.x % NSTRIP;
    const int r0 = strip * HO;
    const int W0 = w * 128;
    const float* __restrict__ xc = x + (size_t)ch * IH * IW;
    const float* __restrict__ yc = y + (size_t)ch * IH * IW;
    const int mc = W0 + 2 * l;                       // main cols 2l,2l+1 (<=510)
    const int hc = min(W0 + 128 + l, IW - 1);        // halo col (lanes 0..9)
    const bool halo = (l < 10);

    // ---- rings: main 2-col float2[11], halo 1-col float[11] (masked) ----
    float2 rx[KS], ry[KS];
    float hx[KS], hy[KS];
#pragma unroll
    for (int i = 0; i < KS; ++i) {
        const int gr = min(r0 + i, IH - 1);
        rx[i] = *(const float2*)(xc + gr * IW + mc);
        ry[i] = *(const float2*)(yc + gr * IW + mc);
    }
    if (halo) {
#pragma unroll
        for (int i = 0; i < KS; ++i) {
            const int gr = min(r0 + i, IH - 1);
            hx[i] = xc[gr * IW + hc];
            hy[i] = yc[gr * IW + hc];
        }
    }
    float2 n0x, n0y, n1x, n1y;
    float h0x = 0.f, h0y = 0.f, h1x = 0.f, h1y = 0.f;
    {
        const int g0 = min(r0 + 11, IH - 1);
        const int g1 = min(r0 + 12, IH - 1);
        n0x = *(const float2*)(xc + g0 * IW + mc);
        n0y = *(const float2*)(yc + g0 * IW + mc);
        n1x = *(const float2*)(xc + g1 * IW + mc);
        n1y = *(const float2*)(yc + g1 * IW + mc);
        if (halo) {
            h0x = xc[g0 * IW + hc];  h0y = yc[g0 * IW + hc];
            h1x = xc[g1 * IW + hc];  h1y = yc[g1 * IW + hc];
        }
    }

    float lsum = 0.f;

    for (int k = 0; k < HO / 2; ++k) {
        // ---- main vblur row A (2k): taps ring[0..10] ----
        {
            float s0[2] = {0.f, 0.f}, s1[2] = {0.f, 0.f}, s2[2] = {0.f, 0.f};
            float s3[2] = {0.f, 0.f}, s4[2] = {0.f, 0.f};
#pragma unroll
            for (int tp = 0; tp < KS; ++tp) {
                const float wg = g_w[tp];
                const float2 xv = rx[tp], yv = ry[tp];
                const float wx0 = wg * xv.x, wx1 = wg * xv.y;
                const float wy0 = wg * yv.x, wy1 = wg * yv.y;
                s0[0] += wx0;  s0[1] += wx1;
                s1[0] += wy0;  s1[1] += wy1;
                s2[0] = fmaf(wx0, xv.x, s2[0]);  s2[1] = fmaf(wx1, xv.y, s2[1]);
                s3[0] = fmaf(wy0, yv.x, s3[0]);  s3[1] = fmaf(wy1, yv.y, s3[1]);
                s4[0] = fmaf(wx0, yv.x, s4[0]);  s4[1] = fmaf(wx1, yv.y, s4[1]);
            }
            *(float2*)&lds[w][0][0][2 * l] = make_float2(s0[0], s0[1]);
            *(float2*)&lds[w][1][0][2 * l] = make_float2(s1[0], s1[1]);
            *(float2*)&lds[w][2][0][2 * l] = make_float2(s2[0], s2[1]);
            *(float2*)&lds[w][3][0][2 * l] = make_float2(s3[0], s3[1]);
            *(float2*)&lds[w][4][0][2 * l] = make_float2(s4[0], s4[1]);
        }
        // ---- main vblur row B (2k+1): taps ring[1..10] + n0 ----
        {
            float s0[2] = {0.f, 0.f}, s1[2] = {0.f, 0.f}, s2[2] = {0.f, 0.f};
            float s3[2] = {0.f, 0.f}, s4[2] = {0.f, 0.f};
#pragma unroll
            for (int tp = 0; tp < KS; ++tp) {
                const float wg = g_w[tp];
                const float2 xv = (tp < KS - 1) ? rx[tp + 1] : n0x;  // static
                const float2 yv = (tp < KS - 1) ? ry[tp + 1] : n0y;
                const float wx0 = wg * xv.x, wx1 = wg * xv.y;
                const float wy0 = wg * yv.x, wy1 = wg * yv.y;
                s0[0] += wx0;  s0[1] += wx1;
                s1[0] += wy0;  s1[1] += wy1;
                s2[0] = fmaf(wx0, xv.x, s2[0]);  s2[1] = fmaf(wx1, xv.y, s2[1]);
                s3[0] = fmaf(wy0, yv.x, s3[0]);  s3[1] = fmaf(wy1, yv.y, s3[1]);
                s4[0] = fmaf(wx0, yv.x, s4[0]);  s4[1] = fmaf(wx1, yv.y, s4[1]);
            }
            *(float2*)&lds[w][0][1][2 * l] = make_float2(s0[0], s0[1]);
            *(float2*)&lds[w][1][1][2 * l] = make_float2(s1[0], s1[1]);
            *(float2*)&lds[w][2][1][2 * l] = make_float2(s2[0], s2[1]);
            *(float2*)&lds[w][3][1][2 * l] = make_float2(s3[0], s3[1]);
            *(float2*)&lds[w][4][1][2 * l] = make_float2(s4[0], s4[1]);
        }
        // ---- halo vblur (lanes 0..9, 1 col each): rows A,B fused ----
        if (halo) {
            float a0 = 0, a1 = 0, a2 = 0, a3 = 0, a4 = 0;
            float b0 = 0, b1 = 0, b2 = 0, b3 = 0, b4 = 0;
#pragma unroll
            for (int tp = 0; tp < KS; ++tp) {
                const float wg = g_w[tp];
                const float xv = hx[tp], yv = hy[tp];
                const float wx = wg * xv, wy = wg * yv;
                a0 += wx;  a1 += wy;
                a2 = fmaf(wx, xv, a2);  a3 = fmaf(wy, yv, a3);  a4 = fmaf(wx, yv, a4);
                const float xw = (tp < KS - 1) ? hx[tp + 1] : h0x;
                const float yw = (tp < KS - 1) ? hy[tp + 1] : h0y;
                const float vx = wg * xw, vy = wg * yw;
                b0 += vx;  b1 += vy;
                b2 = fmaf(vx, xw, b2);  b3 = fmaf(vy, yw, b3);  b4 = fmaf(vx, yw, b4);
            }
            lds[w][0][0][128 + l] = a0;  lds[w][1][0][128 + l] = a1;
            lds[w][2][0][128 + l] = a2;  lds[w][3][0][128 + l] = a3;
            lds[w][4][0][128 + l] = a4;
            lds[w][0][1][128 + l] = b0;  lds[w][1][1][128 + l] = b1;
            lds[w][2][1][128 + l] = b2;  lds[w][3][1][128 + l] = b3;
            lds[w][4][1][128 + l] = b4;
        }
        WAITLDS();   // same-wave RAW: writes complete before reads consume

        // ---- shift rings by 2, commit prefetch, issue next prefetch ----
#pragma unroll
        for (int i = 0; i < KS - 2; ++i) { rx[i] = rx[i + 2]; ry[i] = ry[i + 2]; }
        rx[KS - 2] = n0x; ry[KS - 2] = n0y;
        rx[KS - 1] = n1x; ry[KS - 1] = n1y;
        {
            const int g0 = min(r0 + 2 * k + 13, IH - 1);
            const int g1 = min(r0 + 2 * k + 14, IH - 1);
            n0x = *(const float2*)(xc + g0 * IW + mc);
            n0y = *(const float2*)(yc + g0 * IW + mc);
            n1x = *(const float2*)(xc + g1 * IW + mc);
            n1y = *(const float2*)(yc + g1 * IW + mc);
            if (halo) {
#pragma unroll
                for (int i = 0; i < KS - 2; ++i) { hx[i] = hx[i + 2]; hy[i] = hy[i + 2]; }
                hx[KS - 2] = h0x; hy[KS - 2] = h0y;
                hx[KS - 1] = h1x; hy[KS - 1] = h1y;
                h0x = xc[g0 * IW + hc];  h0y = yc[g0 * IW + hc];
                h1x = xc[g1 * IW + hc];  h1y = yc[g1 * IW + hc];
            }
        }

        // ---- hblur + ssim: 64 lanes = 2 rows x 32 chunks of 4 cols ----
        {
            const int rr = l >> 5;
            const int c4 = 4 * (l & 31);
            const int orow = r0 + 2 * k + rr;
            float m[5][4];
#pragma unroll
            for (int q = 0; q < 5; ++q) {
                float f[16];
#pragma unroll
                for (int a = 0; a < 4; ++a)
                    *(float4*)&f[4 * a] = *(const float4*)&lds[w][q][rr][c4 + 4 * a];
#pragma unroll
                for (int cc = 0; cc < 4; ++cc) {
                    float s = 0.f;
#pragma unroll
                    for (int tp = 0; tp < KS; ++tp) s = fmaf(g_w[tp], f[cc + tp], s);
                    m[q][cc] = s;
                }
            }
            if (orow < OH) {
#pragma unroll
                for (int cc = 0; cc < 4; ++cc) {
                    const int oc = W0 + c4 + cc;
                    if (oc < OW) {
                        const float mux2 = m[0][cc] * m[0][cc];
                        const float muy2 = m[1][cc] * m[1][cc];
                        const float muxy = m[0][cc] * m[1][cc];
                        const float vx = m[2][cc] - mux2;
                        const float vy = m[3][cc] - muy2;
                        const float cxy = m[4][cc] - muxy;
                        const float num = (2.f * muxy + C1f) * (2.f * cxy + C2f);
                        const float den = (mux2 + muy2 + C1f) * (vx + vy + C2f);
                        float r = __builtin_amdgcn_rcpf(den);
                        r = r * fmaf(-den, r, 2.0f);   // Newton step
                        lsum = fmaf(num, r, lsum);
                    }
                }
            }
        }
        WAITLDS();   // same-wave WAR: reads returned before next iter's writes
    }

    // ---- block reduce (4 waves of 64) + last-block finalize ----
#pragma unroll
    for (int off = 32; off > 0; off >>= 1) lsum += __shfl_down(lsum, off, 64);
    if (l == 0) red[w] = lsum;
    __syncthreads();
    if (t == 0) {
        const float bs = (red[0] + red[1]) + (red[2] + red[3]);
        atomicAdd(acc, (double)bs);
        __threadfence();
        const unsigned int prev = atomicAdd(cnt, 1u);
        if (prev == (unsigned int)(NBLK - 1)) {
            const double total = atomicAdd(acc, 0.0);  // coherent read
            out[0] = (float)(1.0 - total / 12096192.0);  // 48*502*502
        }
    }
}

extern "C" void kernel_launch(void* const* d_in, const int* in_sizes, int n_in,
                              void* d_out, int out_size, void* d_ws, size_t ws_size,
                              hipStream_t stream) {
    const float* x = (const float*)d_in[0];
    const float* y = (const float*)d_in[1];
    float* out = (float*)d_out;
    double* acc = (double*)d_ws;
    unsigned int* cnt = (unsigned int*)((char*)d_ws + 8);

    hipMemsetAsync(d_ws, 0, 16, stream);
    ssim_main<<<NBLK, NT, 0, stream>>>(x, y, acc, cnt, out);
}

// Round 14
// 83.923 us; speedup vs baseline: 1.1973x; 1.1973x over previous
//
#include <hip/hip_runtime.h>

#define IH 512
#define IW 512
#define OH 502
#define OW 502
#define KS 11
#define HO 16                 /* output rows per strip */
#define NSTRIP 32             /* 32 strips of 16 rows */
#define NCH 48                /* 16*3 */
#define NBLK (NCH * NSTRIP)   /* 1536 = 6 blocks/CU */
#define NT 256                /* 256 threads * 2 cols = 512 cols */
#define LROW 528              /* padded LDS row (max read idx 523) */
#define C1f 0.0001f
#define C2f 0.0009f

// Gaussian(sigma=1.5, k=11) weights, precomputed in double precision.
__device__ __constant__ float g_w[KS] = {
    0.00102838f, 0.00759876f, 0.03600077f, 0.10936069f, 0.21300554f,
    0.26601173f, 0.21300554f, 0.10936069f, 0.03600077f, 0.00759876f,
    0.00102838f};

// Raw barrier: drain LDS ops (cross-wave visibility) but leave global
// prefetch loads in flight across the barrier (no vmcnt drain).
#define BARRIER() do {                                        \
    asm volatile("s_waitcnt lgkmcnt(0)" ::: "memory");        \
    __builtin_amdgcn_s_barrier();                             \
} while (0)

__global__ __launch_bounds__(NT, 2) void ssim_main(const float* __restrict__ x,
                                                   const float* __restrict__ y,
                                                   double* __restrict__ acc,
                                                   unsigned int* __restrict__ cnt,
                                                   float* __restrict__ out) {
    __shared__ float lds[5][2][LROW];   /* 5 quantities x 2 rows */
    __shared__ float red[4];

    const int t = threadIdx.x;            // owns input cols 2t, 2t+1
    const int ch = blockIdx.x / NSTRIP;
    const int strip = blockIdx.x % NSTRIP;
    const int r0 = strip * HO;
    const float* __restrict__ xc = x + (size_t)ch * IH * IW + 2 * t;
    const float* __restrict__ yc = y + (size_t)ch * IH * IW + 2 * t;

    // ---- warmup: ring holds input rows r0 .. r0+10 (static indices) ----
    float2 rx[KS], ry[KS];
#pragma unroll
    for (int i = 0; i < KS; ++i) {
        const int gr = min(r0 + i, IH - 1);
        rx[i] = *(const float2*)(xc + gr * IW);
        ry[i] = *(const float2*)(yc + gr * IW);
    }
    float2 nx0, ny0, nx1, ny1;
    {
        const int g0 = min(r0 + 11, IH - 1);
        const int g1 = min(r0 + 12, IH - 1);
        nx0 = *(const float2*)(xc + g0 * IW);
        ny0 = *(const float2*)(yc + g0 * IW);
        nx1 = *(const float2*)(xc + g1 * IW);
        ny1 = *(const float2*)(yc + g1 * IW);
    }

    float lsum = 0.f;

    // unroll 4: ring shifts collapse via register renaming (one shift-by-8
    // per 4 iterations instead of four shift-by-2s).
#pragma unroll 4
    for (int k = 0; k < HO / 2; ++k) {
        // ---- vblur row A (2k): taps ring[0..10] ----
        {
            float s0[2] = {0.f, 0.f}, s1[2] = {0.f, 0.f}, s2[2] = {0.f, 0.f};
            float s3[2] = {0.f, 0.f}, s4[2] = {0.f, 0.f};
#pragma unroll
            for (int tp = 0; tp < KS; ++tp) {
                const float w = g_w[tp];
                const float2 xv = rx[tp];
                const float2 yv = ry[tp];
                const float wx0 = w * xv.x, wx1 = w * xv.y;
                const float wy0 = w * yv.x, wy1 = w * yv.y;
                s0[0] += wx0;  s0[1] += wx1;
                s1[0] += wy0;  s1[1] += wy1;
                s2[0] = fmaf(wx0, xv.x, s2[0]);  s2[1] = fmaf(wx1, xv.y, s2[1]);
                s3[0] = fmaf(wy0, yv.x, s3[0]);  s3[1] = fmaf(wy1, yv.y, s3[1]);
                s4[0] = fmaf(wx0, yv.x, s4[0]);  s4[1] = fmaf(wx1, yv.y, s4[1]);
            }
            *(float2*)&lds[0][0][2 * t] = make_float2(s0[0], s0[1]);
            *(float2*)&lds[1][0][2 * t] = make_float2(s1[0], s1[1]);
            *(float2*)&lds[2][0][2 * t] = make_float2(s2[0], s2[1]);
            *(float2*)&lds[3][0][2 * t] = make_float2(s3[0], s3[1]);
            *(float2*)&lds[4][0][2 * t] = make_float2(s4[0], s4[1]);
        }
        // ---- vblur row B (2k+1): taps ring[1..10] + nx0/ny0 as tap 10 ----
        {
            float s0[2] = {0.f, 0.f}, s1[2] = {0.f, 0.f}, s2[2] = {0.f, 0.f};
            float s3[2] = {0.f, 0.f}, s4[2] = {0.f, 0.f};
#pragma unroll
            for (int tp = 0; tp < KS; ++tp) {
                const float w = g_w[tp];
                const float2 xv = (tp < KS - 1) ? rx[tp + 1] : nx0;  // static
                const float2 yv = (tp < KS - 1) ? ry[tp + 1] : ny0;
                const float wx0 = w * xv.x, wx1 = w * xv.y;
                const float wy0 = w * yv.x, wy1 = w * yv.y;
                s0[0] += wx0;  s0[1] += wx1;
                s1[0] += wy0;  s1[1] += wy1;
                s2[0] = fmaf(wx0, xv.x, s2[0]);  s2[1] = fmaf(wx1, xv.y, s2[1]);
                s3[0] = fmaf(wy0, yv.x, s3[0]);  s3[1] = fmaf(wy1, yv.y, s3[1]);
                s4[0] = fmaf(wx0, yv.x, s4[0]);  s4[1] = fmaf(wx1, yv.y, s4[1]);
            }
            *(float2*)&lds[0][1][2 * t] = make_float2(s0[0], s0[1]);
            *(float2*)&lds[1][1][2 * t] = make_float2(s1[0], s1[1]);
            *(float2*)&lds[2][1][2 * t] = make_float2(s2[0], s2[1]);
            *(float2*)&lds[3][1][2 * t] = make_float2(s3[0], s3[1]);
            *(float2*)&lds[4][1][2 * t] = make_float2(s4[0], s4[1]);
        }
        BARRIER();   // barrier1: LDS writes visible; prefetch stays in flight

        // ---- issue NEXT prefetch into temps first (enters VMEM queue early),
        // then shift ring by 2 and commit the PREVIOUS prefetch (counted
        // vmcnt wait: 4 newer loads outstanding, no drain) ----
        {
            const int g0 = min(r0 + 2 * k + 13, IH - 1);
            const int g1 = min(r0 + 2 * k + 14, IH - 1);
            const float2 t0x = *(const float2*)(xc + g0 * IW);
            const float2 t0y = *(const float2*)(yc + g0 * IW);
            const float2 t1x = *(const float2*)(xc + g1 * IW);
            const float2 t1y = *(const float2*)(yc + g1 * IW);
#pragma unroll
            for (int i = 0; i < KS - 2; ++i) { rx[i] = rx[i + 2]; ry[i] = ry[i + 2]; }
            rx[KS - 2] = nx0; ry[KS - 2] = ny0;
            rx[KS - 1] = nx1; ry[KS - 1] = ny1;
            nx0 = t0x; ny0 = t0y;
            nx1 = t1x; ny1 = t1y;
        }

        // ---- hblur + ssim: 256 tasks = 2 rows x 128 4-col chunks ----
        {
            const int rr = t >> 7;            // wave-uniform
            const int c4 = (t & 127) * 4;
            const int orow = r0 + 2 * k + rr;
            float m[5][4];
#pragma unroll
            for (int q = 0; q < 5; ++q) {
                float f[16];
#pragma unroll
                for (int a = 0; a < 4; ++a)
                    *(float4*)&f[4 * a] = *(const float4*)&lds[q][rr][c4 + 4 * a];
#pragma unroll
                for (int cc = 0; cc < 4; ++cc) {
                    float s = 0.f;
#pragma unroll
                    for (int tp = 0; tp < KS; ++tp) s = fmaf(g_w[tp], f[cc + tp], s);
                    m[q][cc] = s;
                }
            }
            if (orow < OH) {
#pragma unroll
                for (int cc = 0; cc < 4; ++cc) {
                    const int gc = c4 + cc;
                    if (gc < OW) {
                        const float mux2 = m[0][cc] * m[0][cc];
                        const float muy2 = m[1][cc] * m[1][cc];
                        const float muxy = m[0][cc] * m[1][cc];
                        const float vx = m[2][cc] - mux2;
                        const float vy = m[3][cc] - muy2;
                        const float cxy = m[4][cc] - muxy;
                        const float num = (2.f * muxy + C1f) * (2.f * cxy + C2f);
                        const float den = (mux2 + muy2 + C1f) * (vx + vy + C2f);
                        float r = __builtin_amdgcn_rcpf(den);
                        r = r * fmaf(-den, r, 2.0f);   // Newton step
                        lsum = fmaf(num, r, lsum);
                    }
                }
            }
        }
        BARRIER();   // barrier2: hblur reads done before next iter's writes (WAR)
    }

    // ---- block reduce (4 waves of 64) + last-block finalize ----
#pragma unroll
    for (int off = 32; off > 0; off >>= 1) lsum += __shfl_down(lsum, off, 64);
    const int wave = t >> 6, lane = t & 63;
    if (lane == 0) red[wave] = lsum;
    __syncthreads();
    if (t == 0) {
        const float bs = (red[0] + red[1]) + (red[2] + red[3]);
        atomicAdd(acc, (double)bs);
        __threadfence();
        const unsigned int prev = atomicAdd(cnt, 1u);
        if (prev == (unsigned int)(NBLK - 1)) {
            const double total = atomicAdd(acc, 0.0);  // coherent read
            out[0] = (float)(1.0 - total / 12096192.0);  // 48*502*502
        }
    }
}

extern "C" void kernel_launch(void* const* d_in, const int* in_sizes, int n_in,
                              void* d_out, int out_size, void* d_ws, size_t ws_size,
                              hipStream_t stream) {
    const float* x = (const float*)d_in[0];
    const float* y = (const float*)d_in[1];
    float* out = (float*)d_out;
    double* acc = (double*)d_ws;
    unsigned int* cnt = (unsigned int*)((char*)d_ws + 8);

    hipMemsetAsync(d_ws, 0, 16, stream);
    ssim_main<<<NBLK, NT, 0, stream>>>(x, y, acc, cnt, out);
}